// Round 1
// baseline (768.581 us; speedup 1.0000x reference)
//
#include <hip/hip_runtime.h>
#include <stdint.h>

#define M_DIM 8192
#define K_DIM 4096
#define N_DIM 12288

typedef int v4i __attribute__((ext_vector_type(4)));

// async global->LDS, 16B per lane. LDS dest must be wave-uniform base
// (HW adds lane*16); global src is per-lane.
#define GLDS16(g, l)                                                         \
  __builtin_amdgcn_global_load_lds(                                          \
      (const __attribute__((address_space(1))) void*)(g),                    \
      (__attribute__((address_space(3))) void*)(l), 16, 0, 0)

// ---------------------------------------------------------------------------
// Kernel 1: per-token dynamic int8 quantization.
// One block (256 thr) per row of K=4096 f32. Each thread: 16 elems.
// scale = max(amax,1e-8)/127 ; q = clip(rint(x/scale), -127, 127)
// ---------------------------------------------------------------------------
__global__ __launch_bounds__(256) void quant_rows(const float* __restrict__ x,
                                                  int8_t* __restrict__ xq,
                                                  float* __restrict__ xs) {
  const int row = blockIdx.x;
  const int t = threadIdx.x;
  const float* xr = x + (size_t)row * K_DIM;

  float4 v[4];
  float amax = 0.f;
#pragma unroll
  for (int i = 0; i < 4; ++i) {
    v[i] = reinterpret_cast<const float4*>(xr)[t * 4 + i];
    amax = fmaxf(amax, fmaxf(fmaxf(fabsf(v[i].x), fabsf(v[i].y)),
                             fmaxf(fabsf(v[i].z), fabsf(v[i].w))));
  }
#pragma unroll
  for (int off = 32; off > 0; off >>= 1)
    amax = fmaxf(amax, __shfl_xor(amax, off));

  __shared__ float smax[4];
  if ((t & 63) == 0) smax[t >> 6] = amax;
  __syncthreads();
  amax = fmaxf(fmaxf(smax[0], smax[1]), fmaxf(smax[2], smax[3]));

  const float scale = fmaxf(amax, 1e-8f) / 127.f;

  union {
    int8_t b[16];
    v4i v;
  } p;
  const float* pv = reinterpret_cast<const float*>(v);
#pragma unroll
  for (int i = 0; i < 16; ++i) {
    float r = rintf(pv[i] / scale);  // round-half-to-even == jnp.round
    r = fminf(127.f, fmaxf(-127.f, r));
    p.b[i] = (int8_t)(int)r;
  }
  reinterpret_cast<v4i*>(xq + (size_t)row * K_DIM)[t] = p.v;
  if (t == 0) xs[row] = scale;
}

// ---------------------------------------------------------------------------
// Kernel 2: pack int32-carried weights (values in [-127,127]) into int8.
// 16 elems / thread. Grid = N*K / (256*16) = 12288 blocks.
// ---------------------------------------------------------------------------
__global__ __launch_bounds__(256) void pack_w(const int* __restrict__ w32,
                                              int8_t* __restrict__ w8) {
  const size_t i = ((size_t)blockIdx.x * 256 + threadIdx.x) * 16;
  const int4* src = reinterpret_cast<const int4*>(w32 + i);
  union {
    int8_t b[16];
    v4i v;
  } p;
#pragma unroll
  for (int c = 0; c < 4; ++c) {
    int4 q = src[c];
    p.b[c * 4 + 0] = (int8_t)q.x;
    p.b[c * 4 + 1] = (int8_t)q.y;
    p.b[c * 4 + 2] = (int8_t)q.z;
    p.b[c * 4 + 3] = (int8_t)q.w;
  }
  *reinterpret_cast<v4i*>(w8 + i) = p.v;
}

// ---------------------------------------------------------------------------
// Kernel 3: int8 GEMM, m97-structure 128x128 tile, BK=64, 4 waves (2x2),
// mfma_i32_16x16x64_i8, fused dequant epilogue.
// C[m][n] = sum_k xq[m][k]*w8[n][k]; out = C * xs[m] * wsc[n] + bias[n]
// ---------------------------------------------------------------------------
#define BM 128
#define BN 128
#define BK 64

__global__ __launch_bounds__(256) void gemm_i8(const int8_t* __restrict__ xq,
                                               const float* __restrict__ xs,
                                               const int8_t* __restrict__ w8,
                                               const float* __restrict__ wsc,
                                               const float* __restrict__ bias,
                                               float* __restrict__ out) {
  __shared__ int8_t As[BM][BK];  // 8 KB, 64B rows
  __shared__ int8_t Bs[BN][BK];  // 8 KB

  const int t = threadIdx.x;
  const int lane = t & 63;
  const int w = t >> 6;
  const int wr = w >> 1;       // wave row 0..1 (64 rows each)
  const int wc = w & 1;        // wave col 0..1 (64 cols each)
  const int fr = lane & 15;    // row/col within 16x16 fragment
  const int kq = lane >> 4;    // k-quadrant: 16 bytes each

  // bijective XCD swizzle (nwg = 6144, 6144 % 8 == 0)
  const int NT_N = N_DIM / BN;              // 96
  const int nwg = (M_DIM / BM) * NT_N;      // 6144
  int bid = (int)blockIdx.x;
  bid = (bid % 8) * (nwg / 8) + bid / 8;
  const int rowBase = (bid / NT_N) * BM;
  const int colBase = (bid % NT_N) * BN;

  // staging: thread t covers LDS bytes [t*16, t*16+16) => row t>>2, col (t&3)*16
  const int srow = t >> 2;
  const int scol = (t & 3) * 16;
  const int8_t* gA = xq + (size_t)(rowBase + srow) * K_DIM + scol;
  const int8_t* gB = w8 + (size_t)(colBase + srow) * K_DIM + scol;
  int8_t* lA = &As[0][0] + w * 1024;  // wave-uniform base
  int8_t* lB = &Bs[0][0] + w * 1024;

  v4i acc[4][4];
#pragma unroll
  for (int i = 0; i < 4; ++i)
#pragma unroll
    for (int j = 0; j < 4; ++j) acc[i][j] = (v4i){0, 0, 0, 0};

  for (int k0 = 0; k0 < K_DIM; k0 += BK) {
    // stage A (rows 0-63 then 64-127) and B, 16B/lane async
    GLDS16(gA + k0, lA);
    GLDS16(gA + k0 + (size_t)64 * K_DIM, lA + 4096);
    GLDS16(gB + k0, lB);
    GLDS16(gB + k0 + (size_t)64 * K_DIM, lB + 4096);
    __syncthreads();  // compiler drains vmcnt+lgkmcnt before s_barrier

    v4i af[4], bf[4];
#pragma unroll
    for (int i = 0; i < 4; ++i)
      af[i] = *reinterpret_cast<const v4i*>(&As[wr * 64 + i * 16 + fr][kq * 16]);
#pragma unroll
    for (int j = 0; j < 4; ++j)
      bf[j] = *reinterpret_cast<const v4i*>(&Bs[wc * 64 + j * 16 + fr][kq * 16]);

#pragma unroll
    for (int i = 0; i < 4; ++i)
#pragma unroll
      for (int j = 0; j < 4; ++j)
        acc[i][j] =
            __builtin_amdgcn_mfma_i32_16x16x64_i8(af[i], bf[j], acc[i][j], 0, 0, 0);

    __syncthreads();  // protect LDS before next-iter staging
  }

  // epilogue: C/D layout col = lane&15, row = (lane>>4)*4 + reg
  const int orow0 = rowBase + wr * 64;
  const int ocol0 = colBase + wc * 64;
  const int rsub = (lane >> 4) * 4;
#pragma unroll
  for (int j = 0; j < 4; ++j) {
    const int col = ocol0 + j * 16 + fr;
    const float wsf = wsc[col];
    const float bb = bias[col];
#pragma unroll
    for (int i = 0; i < 4; ++i) {
      const int row = orow0 + i * 16 + rsub;
#pragma unroll
      for (int r = 0; r < 4; ++r) {
        const float xsf = xs[row + r];
        out[(size_t)(row + r) * N_DIM + col] =
            (float)acc[i][j][r] * xsf * wsf + bb;
      }
    }
  }
}

// ---------------------------------------------------------------------------
extern "C" void kernel_launch(void* const* d_in, const int* in_sizes, int n_in,
                              void* d_out, int out_size, void* d_ws,
                              size_t ws_size, hipStream_t stream) {
  const float* x = (const float*)d_in[0];
  const int* w32 = (const int*)d_in[1];       // int8 values carried as int32
  const float* wscale = (const float*)d_in[2];
  const float* bias = (const float*)d_in[3];
  float* out = (float*)d_out;

  // workspace layout: xq [M*K int8] | xs [M f32] | w8 [N*K int8]
  int8_t* xq = (int8_t*)d_ws;
  float* xs = (float*)((char*)d_ws + (size_t)M_DIM * K_DIM);
  int8_t* w8 = (int8_t*)((char*)d_ws + (size_t)M_DIM * K_DIM + M_DIM * 4);

  quant_rows<<<M_DIM, 256, 0, stream>>>(x, xq, xs);
  pack_w<<<(N_DIM * K_DIM) / (256 * 16), 256, 0, stream>>>(w32, w8);
  gemm_i8<<<(M_DIM / BM) * (N_DIM / BN), 256, 0, stream>>>(xq, xs, w8, wscale,
                                                           bias, out);
}

// Round 2
// 506.133 us; speedup vs baseline: 1.5185x; 1.5185x over previous
//
#include <hip/hip_runtime.h>
#include <stdint.h>

#define M_DIM 8192
#define K_DIM 4096
#define N_DIM 12288

typedef int v4i __attribute__((ext_vector_type(4)));

#define GLDS16(g, l)                                                         \
  __builtin_amdgcn_global_load_lds(                                          \
      (const __attribute__((address_space(1))) void*)(g),                    \
      (__attribute__((address_space(3))) void*)(l), 16, 0, 0)

#define BARRIER() asm volatile("s_barrier" ::: "memory")
#define VMCNT4() asm volatile("s_waitcnt vmcnt(4)" ::: "memory")
#define VMCNT0() asm volatile("s_waitcnt vmcnt(0)" ::: "memory")

// ---------------------------------------------------------------------------
// Kernel 1: per-token dynamic int8 quantization (unchanged from R1, passed).
// ---------------------------------------------------------------------------
__global__ __launch_bounds__(256) void quant_rows(const float* __restrict__ x,
                                                  int8_t* __restrict__ xq,
                                                  float* __restrict__ xs) {
  const int row = blockIdx.x;
  const int t = threadIdx.x;
  const float* xr = x + (size_t)row * K_DIM;

  float4 v[4];
  float amax = 0.f;
#pragma unroll
  for (int i = 0; i < 4; ++i) {
    v[i] = reinterpret_cast<const float4*>(xr)[t * 4 + i];
    amax = fmaxf(amax, fmaxf(fmaxf(fabsf(v[i].x), fabsf(v[i].y)),
                             fmaxf(fabsf(v[i].z), fabsf(v[i].w))));
  }
#pragma unroll
  for (int off = 32; off > 0; off >>= 1)
    amax = fmaxf(amax, __shfl_xor(amax, off));

  __shared__ float smax[4];
  if ((t & 63) == 0) smax[t >> 6] = amax;
  __syncthreads();
  amax = fmaxf(fmaxf(smax[0], smax[1]), fmaxf(smax[2], smax[3]));

  const float scale = fmaxf(amax, 1e-8f) / 127.f;

  union {
    int8_t b[16];
    v4i v;
  } p;
  const float* pv = reinterpret_cast<const float*>(v);
#pragma unroll
  for (int i = 0; i < 16; ++i) {
    float r = rintf(pv[i] / scale);
    r = fminf(127.f, fmaxf(-127.f, r));
    p.b[i] = (int8_t)(int)r;
  }
  reinterpret_cast<v4i*>(xq + (size_t)row * K_DIM)[t] = p.v;
  if (t == 0) xs[row] = scale;
}

// ---------------------------------------------------------------------------
// Kernel 2: pack int32-carried weights into int8 (unchanged from R1).
// ---------------------------------------------------------------------------
__global__ __launch_bounds__(256) void pack_w(const int* __restrict__ w32,
                                              int8_t* __restrict__ w8) {
  const size_t i = ((size_t)blockIdx.x * 256 + threadIdx.x) * 16;
  const int4* src = reinterpret_cast<const int4*>(w32 + i);
  union {
    int8_t b[16];
    v4i v;
  } p;
#pragma unroll
  for (int c = 0; c < 4; ++c) {
    int4 q = src[c];
    p.b[c * 4 + 0] = (int8_t)q.x;
    p.b[c * 4 + 1] = (int8_t)q.y;
    p.b[c * 4 + 2] = (int8_t)q.z;
    p.b[c * 4 + 3] = (int8_t)q.w;
  }
  *reinterpret_cast<v4i*>(w8 + i) = p.v;
}

// ---------------------------------------------------------------------------
// Kernel 3: int8 GEMM, 256x256 tile, BK=128 bytes, 8 waves (2Mx4N),
// 8-phase-per-2-tiles schedule with counted vmcnt (T3+T4), LDS XOR swizzle
// (T2, inverse-swizzled global source + swizzled ds_read), setprio (T5),
// XCD-aware block swizzle (T1). mfma_i32_16x16x64_i8, fused dequant epilogue.
// ---------------------------------------------------------------------------
#define BM 256
#define BN 256
#define BKB 128                 // K elements (=bytes) per tile
#define NTILES (K_DIM / BKB)    // 32

__global__ __launch_bounds__(512, 2) void gemm_i8(
    const int8_t* __restrict__ xq, const float* __restrict__ xs,
    const int8_t* __restrict__ w8, const float* __restrict__ wsc,
    const float* __restrict__ bias, float* __restrict__ out) {
  // LDS map: As[c] at c*32768 (256 rows x 128B), Bs[c] at 65536 + c*32768.
  __shared__ __align__(16) int8_t lds[131072];
  const v4i* Lv = (const v4i*)lds;

  const int t = threadIdx.x;
  const int lane = t & 63;
  const int w = t >> 6;     // wave 0..7
  const int wr = w >> 2;    // 0..1 -> 128-row block
  const int wc = w & 3;     // 0..3 -> 64-col block
  const int fr = lane & 15;
  const int kq = lane >> 4; // 0..3
  const int l7 = lane & 7;

  const int NT_N = N_DIM / BN;            // 48
  const int nwg = (M_DIM / BM) * NT_N;    // 1536, %8==0 -> simple XCD swizzle
  int bid = (int)blockIdx.x;
  bid = (bid & 7) * (nwg >> 3) + (bid >> 3);
  const int rowBase = (bid / NT_N) * BM;
  const int colBase = (bid % NT_N) * BN;

  // staging: one GLDS16/thread covers 64 rows x 128B (8KB). thread t ->
  // row r0 + (t>>3), lds slot t&7. Inverse swizzle on the GLOBAL source:
  // lds(R,S) must hold global k-chunk (S ^ (R&7)); R&7 == (t>>3)&7.
  const int srow = t >> 3;
  const int gslot = (t & 7) ^ (srow & 7);
  const int8_t* gA = xq + (size_t)(rowBase + srow) * K_DIM + gslot * 16;
  const int8_t* gB = w8 + (size_t)(colBase + srow) * K_DIM + gslot * 16;
  int8_t* ldsw = lds + w * 1024;  // wave-uniform dest base (HW adds lane*16)

#define STAGE_A(c, r0, k0) \
  GLDS16(gA + (size_t)(r0) * K_DIM + (k0), ldsw + (c) * 32768 + (r0) * 128)
#define STAGE_B(c, r0, k0) \
  GLDS16(gB + (size_t)(r0) * K_DIM + (k0), ldsw + 65536 + (c) * 32768 + (r0) * 128)

  // swizzled read slot: (ks*4 + kq) ^ (row&7), row&7 == l7
  const int s0_ = kq ^ l7;        // ks=0
  const int s1_ = s0_ ^ 4;        // ks=1
  const int rA = wr * 128 + fr;   // + mh*64 + mi*16
  const int rB = wc * 64 + fr;    // + ni*16

#define LA(c, mh, mi, ks) \
  Lv[((c) << 11) + ((rA + (mh) * 64 + (mi) * 16) << 3) + ((ks) ? s1_ : s0_)]
#define LB(c, ni, ks) \
  Lv[4096 + ((c) << 11) + ((rB + (ni) * 16) << 3) + ((ks) ? s1_ : s0_)]

  v4i acc[8][4];
#pragma unroll
  for (int i = 0; i < 8; ++i)
#pragma unroll
    for (int j = 0; j < 4; ++j) acc[i][j] = (v4i){0, 0, 0, 0};

  // prologue: tile0 (8 stages, buf0) + tile1 A (4 stages, buf1)
  STAGE_A(0, 0, 0); STAGE_A(0, 64, 0); STAGE_A(0, 128, 0); STAGE_A(0, 192, 0);
  STAGE_B(0, 0, 0); STAGE_B(0, 64, 0); STAGE_B(0, 128, 0); STAGE_B(0, 192, 0);
  STAGE_A(1, 0, BKB); STAGE_A(1, 64, BKB); STAGE_A(1, 128, BKB); STAGE_A(1, 192, BKB);
  VMCNT4();   // tile0 fully landed (4 newest = tile1 A)
  BARRIER();

  v4i af[4], bf[4];

  // one phase: ds-load subtile, issue stage, barrier, MFMA burst, barrier
#define PHASE(c, MH, KS, LOADB, ...)                                          \
  {                                                                           \
    _Pragma("unroll") for (int mi = 0; mi < 4; ++mi)                          \
        af[mi] = LA(c, MH, mi, KS);                                           \
    if (LOADB) {                                                              \
      _Pragma("unroll") for (int ni = 0; ni < 4; ++ni)                        \
          bf[ni] = LB(c, ni, KS);                                             \
    }                                                                         \
    __VA_ARGS__                                                               \
    BARRIER();                                                                \
    __builtin_amdgcn_s_setprio(1);                                            \
    _Pragma("unroll") for (int ni = 0; ni < 4; ++ni)                          \
        _Pragma("unroll") for (int mi = 0; mi < 4; ++mi)                      \
            acc[(MH) * 4 + mi][ni] = __builtin_amdgcn_mfma_i32_16x16x64_i8(   \
                af[mi], bf[ni], acc[(MH) * 4 + mi][ni], 0, 0, 0);             \
    __builtin_amdgcn_s_setprio(0);                                            \
    BARRIER();                                                                \
  }

  for (int tt = 0; tt < NTILES - 2; ++tt) {
    const int c = tt & 1;
    const int k1 = (tt + 1) * BKB;
    const int k2 = (tt + 2) * BKB;
    PHASE(c, 0, 0, 1, STAGE_B(c ^ 1, 0, k1); STAGE_B(c ^ 1, 64, k1);)
    PHASE(c, 1, 0, 0, STAGE_B(c ^ 1, 128, k1); STAGE_B(c ^ 1, 192, k1);)
    PHASE(c, 0, 1, 1, )
    PHASE(c, 1, 1, 0, )
    // boundary: buf c just freed -> stage tile tt+2's A there, counted wait
    STAGE_A(c, 0, k2); STAGE_A(c, 64, k2); STAGE_A(c, 128, k2); STAGE_A(c, 192, k2);
    VMCNT4();  // all of tile tt+1 landed; only tt+2's 4 A-stages in flight
    BARRIER();
  }
  {  // tt = NTILES-2 (c=0): stage last tile's B, then full drain
    const int k1 = (NTILES - 1) * BKB;
    PHASE(0, 0, 0, 1, STAGE_B(1, 0, k1); STAGE_B(1, 64, k1);)
    PHASE(0, 1, 0, 0, STAGE_B(1, 128, k1); STAGE_B(1, 192, k1);)
    PHASE(0, 0, 1, 1, )
    PHASE(0, 1, 1, 0, )
    VMCNT0();
    BARRIER();
  }
  {  // tt = NTILES-1 (c=1): compute only
    PHASE(1, 0, 0, 1, )
    PHASE(1, 1, 0, 0, )
    PHASE(1, 0, 1, 1, )
    PHASE(1, 1, 1, 0, )
  }

  // epilogue: C/D layout col = lane&15, row = (lane>>4)*4 + reg
  const int orow0 = rowBase + wr * 128;
  const int ocol0 = colBase + wc * 64;
  const int rsub = kq * 4;
#pragma unroll
  for (int mi8 = 0; mi8 < 8; ++mi8) {
    const int r0 = orow0 + mi8 * 16 + rsub;
    float s4[4];
#pragma unroll
    for (int r = 0; r < 4; ++r) s4[r] = xs[r0 + r];
#pragma unroll
    for (int ni = 0; ni < 4; ++ni) {
      const int col = ocol0 + ni * 16 + fr;
      const float wf = wsc[col];
      const float bb = bias[col];
#pragma unroll
      for (int r = 0; r < 4; ++r)
        out[(size_t)(r0 + r) * N_DIM + col] =
            (float)acc[mi8][ni][r] * s4[r] * wf + bb;
    }
  }
}

// ---------------------------------------------------------------------------
extern "C" void kernel_launch(void* const* d_in, const int* in_sizes, int n_in,
                              void* d_out, int out_size, void* d_ws,
                              size_t ws_size, hipStream_t stream) {
  const float* x = (const float*)d_in[0];
  const int* w32 = (const int*)d_in[1];
  const float* wscale = (const float*)d_in[2];
  const float* bias = (const float*)d_in[3];
  float* out = (float*)d_out;

  int8_t* xq = (int8_t*)d_ws;
  float* xs = (float*)((char*)d_ws + (size_t)M_DIM * K_DIM);
  int8_t* w8 = (int8_t*)((char*)d_ws + (size_t)M_DIM * K_DIM + M_DIM * 4);

  quant_rows<<<M_DIM, 256, 0, stream>>>(x, xq, xs);
  pack_w<<<(N_DIM * K_DIM) / (256 * 16), 256, 0, stream>>>(w32, w8);
  gemm_i8<<<(M_DIM / BM) * (N_DIM / BN), 512, 0, stream>>>(xq, xs, w8, wscale,
                                                           bias, out);
}